// Round 1
// baseline (339.737 us; speedup 1.0000x reference)
//
#include <hip/hip_runtime.h>
#include <math.h>

#define EMBED 1024
#define NHEAD 16
#define HDIM  64
#define CLEN  16384

typedef float f4 __attribute__((ext_vector_type(4)));

// ---- workspace layout (float offsets) ----
#define WS_QKV   0          // q[1024] | k_i[1024] | v_i[1024]
#define WS_QP    3072       // qkv split-K partials [3*64*1024]
#define WS_PM    199680     // block-partial m   [1024*16]
#define WS_PL    216064     // block-partial l   [1024*16]
#define WS_PACC  232448     // block-partial acc [1024*1024]
#define WS_GM    1281024    // group m   [32*16]
#define WS_GL    1281536    // group l   [32*16]
#define WS_GACC  1282048    // group acc [32*1024]
#define WS_OPART 1314816    // out-proj partials [64*1024]
// total = 1380352 floats ~= 5.52 MB

// ---------------------------------------------------------------------------
// A: q/k/v projection split-K partials. 192 blocks = 3 matrices x 64 K-chunks
// of 16 rows; thread owns 4 consecutive columns (float4). NO atomics.
// ---------------------------------------------------------------------------
__global__ __launch_bounds__(256) void qkv_proj(
    const float* __restrict__ x,
    const float* __restrict__ Wq,
    const float* __restrict__ Wk,
    const float* __restrict__ Wv,
    float* __restrict__ ws) {
  int m = blockIdx.x >> 6;             // 0:q 1:k 2:v
  int c = blockIdx.x & 63;             // K-chunk
  const float* W = (m == 0) ? Wq : (m == 1) ? Wk : Wv;
  int j = threadIdx.x << 2;
  int i0 = c * 16;
  float4 acc = make_float4(0.f, 0.f, 0.f, 0.f);
  for (int i = i0; i < i0 + 16; ++i) {
    float xv = x[i];
    float4 w = *(const float4*)(W + (size_t)i * EMBED + j);
    acc.x += xv * w.x; acc.y += xv * w.y;
    acc.z += xv * w.z; acc.w += xv * w.w;
  }
  *(float4*)(ws + WS_QP + (size_t)(m * 64 + c) * EMBED + j) = acc;
}

// A2: reduce 64 partials + bias -> q/k/v. 12 blocks x 256.
__global__ __launch_bounds__(256) void qkv_reduce(
    const float* __restrict__ bq, const float* __restrict__ bk,
    const float* __restrict__ bv, float* __restrict__ ws) {
  int m = blockIdx.x >> 2;
  int j = ((blockIdx.x & 3) << 8) + threadIdx.x;
  const float* b = (m == 0) ? bq : (m == 1) ? bk : bv;
  float s = b[j];
  const float* p = ws + WS_QP + (size_t)m * 64 * EMBED + j;
  for (int c = 0; c < 64; ++c) s += p[(size_t)c * EMBED];
  ws[WS_QKV + m * EMBED + j] = s;
}

// ---------------------------------------------------------------------------
// B: fused cache-shift + online-softmax attention, COALESCED layout.
// 1024 blocks x 512 threads (8 waves): wave wv handles positions t0..t0+1
// alone: lane i owns elements {c*256 + i*4 .. +3} for chunks c=0..3, so every
// float4 load/store is a fully-coalesced 1 KB wave transaction.
// Head of (c, lane) chunk = c*4 + lane/16; per-head dot = 16-lane butterfly.
// Per-lane softmax state m[4], l[4] (replicated across each 16-lane group).
// 512-thread blocks + VGPR<=64 (launch_bounds 512,8) -> 32 waves/CU resident
// (2x the previous version) to push memory-level parallelism.
// Shifted-cache stores are NONTEMPORAL: the written cache is never re-read by
// this pipeline, so keep it from thrashing the L2/L3 that serves the reads.
// ---------------------------------------------------------------------------
__global__ __launch_bounds__(512, 8) void shift_attn(
    const float* __restrict__ cache,   // (2, 16384, 1024): v then k
    float* __restrict__ out,           // d_out
    float* __restrict__ ws) {
  __shared__ float sacc[7][EMBED];
  __shared__ float sm[8][NHEAD];
  __shared__ float sl[8][NHEAD];

  const int wv   = threadIdx.x >> 6;   // wave in block 0..7
  const int lane = threadIdx.x & 63;
  const int grp  = lane >> 4;          // 16-lane group 0..3

  float qf[16];
#pragma unroll
  for (int c = 0; c < 4; ++c) {
    float4 t = *(const float4*)(ws + WS_QKV + c * 256 + lane * 4);
    qf[c * 4] = t.x; qf[c * 4 + 1] = t.y; qf[c * 4 + 2] = t.z; qf[c * 4 + 3] = t.w;
  }

  float m[4] = {-INFINITY, -INFINITY, -INFINITY, -INFINITY};
  float l[4] = {0.f, 0.f, 0.f, 0.f};
  float acc[16];
#pragma unroll
  for (int j = 0; j < 16; ++j) acc[j] = 0.f;

  const float* vin = cache;
  const float* kin = cache + (size_t)CLEN * EMBED;
  float* vout = out + EMBED;
  float* kout = out + EMBED + (size_t)CLEN * EMBED;
  const int t0 = blockIdx.x * 16 + wv * 2;

  for (int it = 0; it < 2; ++it) {
    int t = t0 + it;
    const float* vsrc = (t < CLEN - 1) ? (vin + (size_t)(t + 1) * EMBED)
                                       : (ws + WS_QKV + 2 * EMBED);
    const float* ksrc = (t < CLEN - 1) ? (kin + (size_t)(t + 1) * EMBED)
                                       : (ws + WS_QKV + EMBED);
    float vv[16], kk[16];
#pragma unroll
    for (int c = 0; c < 4; ++c) {
      float4 tv = *(const float4*)(vsrc + c * 256 + lane * 4);
      vv[c * 4] = tv.x; vv[c * 4 + 1] = tv.y; vv[c * 4 + 2] = tv.z; vv[c * 4 + 3] = tv.w;
    }
#pragma unroll
    for (int c = 0; c < 4; ++c) {
      float4 tk = *(const float4*)(ksrc + c * 256 + lane * 4);
      kk[c * 4] = tk.x; kk[c * 4 + 1] = tk.y; kk[c * 4 + 2] = tk.z; kk[c * 4 + 3] = tk.w;
    }
    float* vd = vout + (size_t)t * EMBED;
    float* kd = kout + (size_t)t * EMBED;
#pragma unroll
    for (int c = 0; c < 4; ++c) {
      f4 sv = {vv[c * 4], vv[c * 4 + 1], vv[c * 4 + 2], vv[c * 4 + 3]};
      __builtin_nontemporal_store(sv, (f4*)(vd + c * 256 + lane * 4));
    }
#pragma unroll
    for (int c = 0; c < 4; ++c) {
      f4 sk = {kk[c * 4], kk[c * 4 + 1], kk[c * 4 + 2], kk[c * 4 + 3]};
      __builtin_nontemporal_store(sk, (f4*)(kd + c * 256 + lane * 4));
    }

    bool nz = false;
#pragma unroll
    for (int j = 0; j < 16; ++j) nz = nz || (vv[j] != 0.f);

    // per-chunk partial dots, butterfly over the 16-lane group
    float d[4];
#pragma unroll
    for (int c = 0; c < 4; ++c) {
      d[c] = qf[c * 4] * kk[c * 4] + qf[c * 4 + 1] * kk[c * 4 + 1] +
             qf[c * 4 + 2] * kk[c * 4 + 2] + qf[c * 4 + 3] * kk[c * 4 + 3];
    }
#pragma unroll
    for (int msk = 1; msk <= 8; msk <<= 1) {
#pragma unroll
      for (int c = 0; c < 4; ++c) d[c] += __shfl_xor(d[c], msk, 64);
    }

    if (__any((int)nz)) {
#pragma unroll
      for (int c = 0; c < 4; ++c) {
        float s  = d[c] * 0.125f;              // 1/sqrt(64)
        float mn = fmaxf(m[c], s);
        float alpha = __expf(m[c] - mn);       // exp(-inf)=0 on first hit
        float p     = __expf(s - mn);
        l[c] = l[c] * alpha + p;
#pragma unroll
        for (int j = 0; j < 4; ++j)
          acc[c * 4 + j] = acc[c * 4 + j] * alpha + p * vv[c * 4 + j];
        m[c] = mn;
      }
    }
  }

  // intra-block combine: waves 1..7 park partials in LDS, wave 0 merges.
  if (wv > 0) {
#pragma unroll
    for (int c = 0; c < 4; ++c)
      *(float4*)(&sacc[wv - 1][c * 256 + lane * 4]) =
          make_float4(acc[c * 4], acc[c * 4 + 1], acc[c * 4 + 2], acc[c * 4 + 3]);
    if ((lane & 15) == 0) {
#pragma unroll
      for (int c = 0; c < 4; ++c) {
        sm[wv][c * 4 + grp] = m[c];
        sl[wv][c * 4 + grp] = l[c];
      }
    }
  }
  __syncthreads();
  if (wv == 0) {
    for (int w = 1; w < 8; ++w) {
#pragma unroll
      for (int c = 0; c < 4; ++c) {
        float m2 = sm[w][c * 4 + grp];
        float M  = fmaxf(m[c], m2);
        float a1 = (m[c] == -INFINITY) ? 0.f : __expf(m[c] - M);
        float a2 = (m2   == -INFINITY) ? 0.f : __expf(m2 - M);
        l[c] = a1 * l[c] + a2 * sl[w][c * 4 + grp];
        float4 av = *(const float4*)(&sacc[w - 1][c * 256 + lane * 4]);
        acc[c * 4]     = a1 * acc[c * 4]     + a2 * av.x;
        acc[c * 4 + 1] = a1 * acc[c * 4 + 1] + a2 * av.y;
        acc[c * 4 + 2] = a1 * acc[c * 4 + 2] + a2 * av.z;
        acc[c * 4 + 3] = a1 * acc[c * 4 + 3] + a2 * av.w;
        m[c] = M;
      }
    }
    if ((lane & 15) == 0) {
#pragma unroll
      for (int c = 0; c < 4; ++c) {
        ws[WS_PM + blockIdx.x * NHEAD + c * 4 + grp] = m[c];
        ws[WS_PL + blockIdx.x * NHEAD + c * 4 + grp] = l[c];
      }
    }
    float* pa = ws + WS_PACC + (size_t)blockIdx.x * EMBED;
#pragma unroll
    for (int c = 0; c < 4; ++c)
      *(float4*)(pa + c * 256 + lane * 4) =
          make_float4(acc[c * 4], acc[c * 4 + 1], acc[c * 4 + 2], acc[c * 4 + 3]);
  }
}

// C1: 1024 block-partials -> 32 group-partials. 32 blocks x 1024.
__global__ __launch_bounds__(1024) void combine1(float* __restrict__ ws) {
  int g = blockIdx.x, t = threadIdx.x, h = t >> 6;
  int w0 = g * 32;
  float M = -INFINITY;
  for (int w = w0; w < w0 + 32; ++w)
    M = fmaxf(M, ws[WS_PM + w * NHEAD + h]);
  float L = 0.f, a = 0.f;
  for (int w = w0; w < w0 + 32; ++w) {
    float mw = ws[WS_PM + w * NHEAD + h];
    float sc = (mw == -INFINITY) ? 0.f : __expf(mw - M);
    L += sc * ws[WS_PL + w * NHEAD + h];
    a += sc * ws[WS_PACC + (size_t)w * EMBED + t];
  }
  if ((t & 63) == 0) {
    ws[WS_GM + g * NHEAD + h] = M;
    ws[WS_GL + g * NHEAD + h] = L;
  }
  ws[WS_GACC + (size_t)g * EMBED + t] = a;
}

// D (fused combine2 + out-proj partials): 64 blocks x 256.
// Block c covers rows i0 = c*16 .. +15 (all within head i0/64): threads 0..15
// finish the softmax combine for those rows into LDS, then the block does its
// split-K GEMV chunk against Wo.
__global__ __launch_bounds__(256) void out_proj(
    const float* __restrict__ Wo,
    float* __restrict__ ws) {
  __shared__ float svals[16];
  int c = blockIdx.x;
  int i0 = c * 16;
  int h0 = i0 >> 6;
  if (threadIdx.x < 16) {
    int i = i0 + threadIdx.x;
    float M = -INFINITY;
    for (int g = 0; g < 32; ++g)
      M = fmaxf(M, ws[WS_GM + g * NHEAD + h0]);
    float L = 0.f, a = 0.f;
    for (int g = 0; g < 32; ++g) {
      float mg = ws[WS_GM + g * NHEAD + h0];
      float sc = (mg == -INFINITY) ? 0.f : __expf(mg - M);
      L += sc * ws[WS_GL + g * NHEAD + h0];
      a += sc * ws[WS_GACC + (size_t)g * EMBED + i];
    }
    svals[threadIdx.x] = a / L;
  }
  __syncthreads();
  int j = threadIdx.x << 2;
  float4 acc = make_float4(0.f, 0.f, 0.f, 0.f);
  for (int i = 0; i < 16; ++i) {
    float xv = svals[i];
    float4 w = *(const float4*)(Wo + (size_t)(i0 + i) * EMBED + j);
    acc.x += xv * w.x; acc.y += xv * w.y;
    acc.z += xv * w.z; acc.w += xv * w.w;
  }
  *(float4*)(ws + WS_OPART + (size_t)c * EMBED + j) = acc;
}

// D2: reduce 64 partials + bo -> d_out[0:1024]. 1 block x 1024.
__global__ __launch_bounds__(1024) void out_reduce(
    const float* __restrict__ ws, const float* __restrict__ bo,
    float* __restrict__ out) {
  int t = threadIdx.x;
  float s = bo[t];
  const float* p = ws + WS_OPART + t;
  for (int c = 0; c < 64; ++c) s += p[(size_t)c * EMBED];
  out[t] = s;
}

extern "C" void kernel_launch(void* const* d_in, const int* in_sizes, int n_in,
                              void* d_out, int out_size, void* d_ws, size_t ws_size,
                              hipStream_t stream) {
  const float* x     = (const float*)d_in[0];
  const float* cache = (const float*)d_in[1];
  const float* Wv    = (const float*)d_in[2];
  const float* bv    = (const float*)d_in[3];
  const float* Wq    = (const float*)d_in[4];
  const float* bq    = (const float*)d_in[5];
  const float* Wk    = (const float*)d_in[6];
  const float* bk    = (const float*)d_in[7];
  const float* Wo    = (const float*)d_in[8];
  const float* bo    = (const float*)d_in[9];
  float* out = (float*)d_out;
  float* ws  = (float*)d_ws;

  qkv_proj  <<<192, 256, 0, stream>>>(x, Wq, Wk, Wv, ws);
  qkv_reduce<<<12, 256, 0, stream>>>(bq, bk, bv, ws);
  shift_attn<<<1024, 512, 0, stream>>>(cache, out, ws);
  combine1  <<<32, 1024, 0, stream>>>(ws);
  out_proj  <<<64, 256, 0, stream>>>(Wo, ws);
  out_reduce<<<1, 1024, 0, stream>>>(ws, bo, out);
}

// Round 3
// 284.057 us; speedup vs baseline: 1.1960x; 1.1960x over previous
//
#include <hip/hip_runtime.h>
#include <math.h>

#define EMBED 1024
#define NHEAD 16
#define HDIM  64
#define CLEN  16384

// ---- workspace layout (float offsets) ----
#define WS_QKV   0          // q[1024] | k_i[1024] | v_i[1024]
#define WS_QP    3072       // qkv split-K partials [3*64*1024]
#define WS_PM    199680     // block-partial m   [512*16]
#define WS_PL    216064     // block-partial l   [512*16]
#define WS_PACC  232448     // block-partial acc [512*1024]
#define WS_GM    1281024    // group m   [32*16]
#define WS_GL    1281536    // group l   [32*16]
#define WS_GACC  1282048    // group acc [32*1024]
#define WS_OPART 1314816    // out-proj partials [64*1024]
// total = 1380352 floats ~= 5.52 MB (layout unchanged; PM/PL/PACC now use
// only the first 512 rows)

// ---------------------------------------------------------------------------
// A: q/k/v projection split-K partials. 192 blocks = 3 matrices x 64 K-chunks
// of 16 rows; thread owns 4 consecutive columns (float4). NO atomics.
// ---------------------------------------------------------------------------
__global__ __launch_bounds__(256) void qkv_proj(
    const float* __restrict__ x,
    const float* __restrict__ Wq,
    const float* __restrict__ Wk,
    const float* __restrict__ Wv,
    float* __restrict__ ws) {
  int m = blockIdx.x >> 6;             // 0:q 1:k 2:v
  int c = blockIdx.x & 63;             // K-chunk
  const float* W = (m == 0) ? Wq : (m == 1) ? Wk : Wv;
  int j = threadIdx.x << 2;
  int i0 = c * 16;
  float4 acc = make_float4(0.f, 0.f, 0.f, 0.f);
  for (int i = i0; i < i0 + 16; ++i) {
    float xv = x[i];
    float4 w = *(const float4*)(W + (size_t)i * EMBED + j);
    acc.x += xv * w.x; acc.y += xv * w.y;
    acc.z += xv * w.z; acc.w += xv * w.w;
  }
  *(float4*)(ws + WS_QP + (size_t)(m * 64 + c) * EMBED + j) = acc;
}

// A2: reduce 64 partials + bias -> q/k/v. 12 blocks x 256.
__global__ __launch_bounds__(256) void qkv_reduce(
    const float* __restrict__ bq, const float* __restrict__ bk,
    const float* __restrict__ bv, float* __restrict__ ws) {
  int m = blockIdx.x >> 2;
  int j = ((blockIdx.x & 3) << 8) + threadIdx.x;
  const float* b = (m == 0) ? bq : (m == 1) ? bk : bv;
  float s = b[j];
  const float* p = ws + WS_QP + (size_t)m * 64 * EMBED + j;
  for (int c = 0; c < 64; ++c) s += p[(size_t)c * EMBED];
  ws[WS_QKV + m * EMBED + j] = s;
}

// ---------------------------------------------------------------------------
// B: fused cache-shift + online-softmax attention, COALESCED layout.
// 512 blocks x 256 threads; wave wv handles positions t0..t0+7 (8-deep
// t-loop). lane i owns elements {c*256 + i*4 .. +3} for chunks c=0..3, so
// every float4 load/store is a fully-coalesced 1 KB wave transaction.
// Head of (c, lane) chunk = c*4 + lane/16; per-head dot = 16-lane butterfly.
// Per-lane softmax state m[4], l[4] (replicated across each 16-lane group).
//
// History: 256thr/4-iter = 82.7us @28% occ, 2.49 TB/s.
//          512thr/2-iter = 109us  @52% occ, 1.89 TB/s (VGPR fell to 32 ->
//          per-wave load pipeline halved; occupancy did NOT compensate).
// => loop-depth per wave is the lever, not wave count. This version: 8-deep.
// ---------------------------------------------------------------------------
__global__ __launch_bounds__(256) void shift_attn(
    const float* __restrict__ cache,   // (2, 16384, 1024): v then k
    float* __restrict__ out,           // d_out
    float* __restrict__ ws) {
  __shared__ float sacc[3][EMBED];
  __shared__ float sm[4][NHEAD];
  __shared__ float sl[4][NHEAD];

  const int wv   = threadIdx.x >> 6;   // wave in block 0..3
  const int lane = threadIdx.x & 63;
  const int grp  = lane >> 4;          // 16-lane group 0..3

  float qf[16];
#pragma unroll
  for (int c = 0; c < 4; ++c) {
    float4 t = *(const float4*)(ws + WS_QKV + c * 256 + lane * 4);
    qf[c * 4] = t.x; qf[c * 4 + 1] = t.y; qf[c * 4 + 2] = t.z; qf[c * 4 + 3] = t.w;
  }

  float m[4] = {-INFINITY, -INFINITY, -INFINITY, -INFINITY};
  float l[4] = {0.f, 0.f, 0.f, 0.f};
  float acc[16];
#pragma unroll
  for (int j = 0; j < 16; ++j) acc[j] = 0.f;

  const float* vin = cache;
  const float* kin = cache + (size_t)CLEN * EMBED;
  float* vout = out + EMBED;
  float* kout = out + EMBED + (size_t)CLEN * EMBED;
  const int t0 = blockIdx.x * 32 + wv * 8;

  for (int it = 0; it < 8; ++it) {
    int t = t0 + it;
    const float* vsrc = (t < CLEN - 1) ? (vin + (size_t)(t + 1) * EMBED)
                                       : (ws + WS_QKV + 2 * EMBED);
    const float* ksrc = (t < CLEN - 1) ? (kin + (size_t)(t + 1) * EMBED)
                                       : (ws + WS_QKV + EMBED);
    float vv[16], kk[16];
#pragma unroll
    for (int c = 0; c < 4; ++c) {
      float4 tv = *(const float4*)(vsrc + c * 256 + lane * 4);
      vv[c * 4] = tv.x; vv[c * 4 + 1] = tv.y; vv[c * 4 + 2] = tv.z; vv[c * 4 + 3] = tv.w;
    }
#pragma unroll
    for (int c = 0; c < 4; ++c) {
      float4 tk = *(const float4*)(ksrc + c * 256 + lane * 4);
      kk[c * 4] = tk.x; kk[c * 4 + 1] = tk.y; kk[c * 4 + 2] = tk.z; kk[c * 4 + 3] = tk.w;
    }
    float* vd = vout + (size_t)t * EMBED;
    float* kd = kout + (size_t)t * EMBED;
#pragma unroll
    for (int c = 0; c < 4; ++c)
      *(float4*)(vd + c * 256 + lane * 4) =
          make_float4(vv[c * 4], vv[c * 4 + 1], vv[c * 4 + 2], vv[c * 4 + 3]);
#pragma unroll
    for (int c = 0; c < 4; ++c)
      *(float4*)(kd + c * 256 + lane * 4) =
          make_float4(kk[c * 4], kk[c * 4 + 1], kk[c * 4 + 2], kk[c * 4 + 3]);

    bool nz = false;
#pragma unroll
    for (int j = 0; j < 16; ++j) nz = nz || (vv[j] != 0.f);

    // per-chunk partial dots, butterfly over the 16-lane group
    float d[4];
#pragma unroll
    for (int c = 0; c < 4; ++c) {
      d[c] = qf[c * 4] * kk[c * 4] + qf[c * 4 + 1] * kk[c * 4 + 1] +
             qf[c * 4 + 2] * kk[c * 4 + 2] + qf[c * 4 + 3] * kk[c * 4 + 3];
    }
#pragma unroll
    for (int msk = 1; msk <= 8; msk <<= 1) {
#pragma unroll
      for (int c = 0; c < 4; ++c) d[c] += __shfl_xor(d[c], msk, 64);
    }

    if (__any((int)nz)) {
#pragma unroll
      for (int c = 0; c < 4; ++c) {
        float s  = d[c] * 0.125f;              // 1/sqrt(64)
        float mn = fmaxf(m[c], s);
        float alpha = __expf(m[c] - mn);       // exp(-inf)=0 on first hit
        float p     = __expf(s - mn);
        l[c] = l[c] * alpha + p;
#pragma unroll
        for (int j = 0; j < 4; ++j)
          acc[c * 4 + j] = acc[c * 4 + j] * alpha + p * vv[c * 4 + j];
        m[c] = mn;
      }
    }
  }

  // intra-block combine: waves 1..3 park partials in LDS, wave 0 merges.
  if (wv > 0) {
#pragma unroll
    for (int c = 0; c < 4; ++c)
      *(float4*)(&sacc[wv - 1][c * 256 + lane * 4]) =
          make_float4(acc[c * 4], acc[c * 4 + 1], acc[c * 4 + 2], acc[c * 4 + 3]);
    if ((lane & 15) == 0) {
#pragma unroll
      for (int c = 0; c < 4; ++c) {
        sm[wv][c * 4 + grp] = m[c];
        sl[wv][c * 4 + grp] = l[c];
      }
    }
  }
  __syncthreads();
  if (wv == 0) {
    for (int w = 1; w < 4; ++w) {
#pragma unroll
      for (int c = 0; c < 4; ++c) {
        float m2 = sm[w][c * 4 + grp];
        float M  = fmaxf(m[c], m2);
        float a1 = (m[c] == -INFINITY) ? 0.f : __expf(m[c] - M);
        float a2 = (m2   == -INFINITY) ? 0.f : __expf(m2 - M);
        l[c] = a1 * l[c] + a2 * sl[w][c * 4 + grp];
        float4 av = *(const float4*)(&sacc[w - 1][c * 256 + lane * 4]);
        acc[c * 4]     = a1 * acc[c * 4]     + a2 * av.x;
        acc[c * 4 + 1] = a1 * acc[c * 4 + 1] + a2 * av.y;
        acc[c * 4 + 2] = a1 * acc[c * 4 + 2] + a2 * av.z;
        acc[c * 4 + 3] = a1 * acc[c * 4 + 3] + a2 * av.w;
        m[c] = M;
      }
    }
    if ((lane & 15) == 0) {
#pragma unroll
      for (int c = 0; c < 4; ++c) {
        ws[WS_PM + blockIdx.x * NHEAD + c * 4 + grp] = m[c];
        ws[WS_PL + blockIdx.x * NHEAD + c * 4 + grp] = l[c];
      }
    }
    float* pa = ws + WS_PACC + (size_t)blockIdx.x * EMBED;
#pragma unroll
    for (int c = 0; c < 4; ++c)
      *(float4*)(pa + c * 256 + lane * 4) =
          make_float4(acc[c * 4], acc[c * 4 + 1], acc[c * 4 + 2], acc[c * 4 + 3]);
  }
}

// C1: 512 block-partials -> 32 group-partials. 32 blocks x 1024 (16 each).
__global__ __launch_bounds__(1024) void combine1(float* __restrict__ ws) {
  int g = blockIdx.x, t = threadIdx.x, h = t >> 6;
  int w0 = g * 16;
  float M = -INFINITY;
  for (int w = w0; w < w0 + 16; ++w)
    M = fmaxf(M, ws[WS_PM + w * NHEAD + h]);
  float L = 0.f, a = 0.f;
  for (int w = w0; w < w0 + 16; ++w) {
    float mw = ws[WS_PM + w * NHEAD + h];
    float sc = (mw == -INFINITY) ? 0.f : __expf(mw - M);
    L += sc * ws[WS_PL + w * NHEAD + h];
    a += sc * ws[WS_PACC + (size_t)w * EMBED + t];
  }
  if ((t & 63) == 0) {
    ws[WS_GM + g * NHEAD + h] = M;
    ws[WS_GL + g * NHEAD + h] = L;
  }
  ws[WS_GACC + (size_t)g * EMBED + t] = a;
}

// D (fused combine2 + out-proj partials): 64 blocks x 256.
// Block c covers rows i0 = c*16 .. +15 (all within head i0/64): threads 0..15
// finish the softmax combine for those rows into LDS, then the block does its
// split-K GEMV chunk against Wo.
__global__ __launch_bounds__(256) void out_proj(
    const float* __restrict__ Wo,
    float* __restrict__ ws) {
  __shared__ float svals[16];
  int c = blockIdx.x;
  int i0 = c * 16;
  int h0 = i0 >> 6;
  if (threadIdx.x < 16) {
    int i = i0 + threadIdx.x;
    float M = -INFINITY;
    for (int g = 0; g < 32; ++g)
      M = fmaxf(M, ws[WS_GM + g * NHEAD + h0]);
    float L = 0.f, a = 0.f;
    for (int g = 0; g < 32; ++g) {
      float mg = ws[WS_GM + g * NHEAD + h0];
      float sc = (mg == -INFINITY) ? 0.f : __expf(mg - M);
      L += sc * ws[WS_GL + g * NHEAD + h0];
      a += sc * ws[WS_GACC + (size_t)g * EMBED + i];
    }
    svals[threadIdx.x] = a / L;
  }
  __syncthreads();
  int j = threadIdx.x << 2;
  float4 acc = make_float4(0.f, 0.f, 0.f, 0.f);
  for (int i = 0; i < 16; ++i) {
    float xv = svals[i];
    float4 w = *(const float4*)(Wo + (size_t)(i0 + i) * EMBED + j);
    acc.x += xv * w.x; acc.y += xv * w.y;
    acc.z += xv * w.z; acc.w += xv * w.w;
  }
  *(float4*)(ws + WS_OPART + (size_t)c * EMBED + j) = acc;
}

// D2: reduce 64 partials + bo -> d_out[0:1024]. 1 block x 1024.
__global__ __launch_bounds__(1024) void out_reduce(
    const float* __restrict__ ws, const float* __restrict__ bo,
    float* __restrict__ out) {
  int t = threadIdx.x;
  float s = bo[t];
  const float* p = ws + WS_OPART + t;
  for (int c = 0; c < 64; ++c) s += p[(size_t)c * EMBED];
  out[t] = s;
}

extern "C" void kernel_launch(void* const* d_in, const int* in_sizes, int n_in,
                              void* d_out, int out_size, void* d_ws, size_t ws_size,
                              hipStream_t stream) {
  const float* x     = (const float*)d_in[0];
  const float* cache = (const float*)d_in[1];
  const float* Wv    = (const float*)d_in[2];
  const float* bv    = (const float*)d_in[3];
  const float* Wq    = (const float*)d_in[4];
  const float* bq    = (const float*)d_in[5];
  const float* Wk    = (const float*)d_in[6];
  const float* bk    = (const float*)d_in[7];
  const float* Wo    = (const float*)d_in[8];
  const float* bo    = (const float*)d_in[9];
  float* out = (float*)d_out;
  float* ws  = (float*)d_ws;

  qkv_proj  <<<192, 256, 0, stream>>>(x, Wq, Wk, Wv, ws);
  qkv_reduce<<<12, 256, 0, stream>>>(bq, bk, bv, ws);
  shift_attn<<<512, 256, 0, stream>>>(cache, out, ws);
  combine1  <<<32, 1024, 0, stream>>>(ws);
  out_proj  <<<64, 256, 0, stream>>>(Wo, ws);
  out_reduce<<<1, 1024, 0, stream>>>(ws, bo, out);
}